// Round 7
// baseline (84.951 us; speedup 1.0000x reference)
//
#include <hip/hip_runtime.h>

#define NMAX 10
#define KPL  16          // hidden units per lane (1024 / 64)
#define L2E  1.4426950408889634f
#define LN2  0.6931471805599453f
#define NBLK 1024        // persistent grid: 4 blocks/CU on 256 CUs

typedef float f2 __attribute__((ext_vector_type(2)));

// ---------- DPP cross-lane sum (VALU pipe only) ----------
template<int CTRL, int RMASK, int BMASK>
__device__ __forceinline__ float dppmov(float v) {
    return __int_as_float(__builtin_amdgcn_update_dpp(
        0, __float_as_int(v), CTRL, RMASK, BMASK, true));
}
__device__ __forceinline__ float rdlane63(float v) {
    return __int_as_float(__builtin_amdgcn_readlane(__float_as_int(v), 63));
}

// two independent wave64 sums -> uniform scalars (2 chains for ILP)
__device__ __forceinline__ void wred2(float& a, float& b) {
    a += dppmov<0xB1, 0xf, 0xf>(a);  b += dppmov<0xB1, 0xf, 0xf>(b);  // quad xor1
    a += dppmov<0x4E, 0xf, 0xf>(a);  b += dppmov<0x4E, 0xf, 0xf>(b);  // quad xor2
    a += dppmov<0x141,0xf, 0xf>(a);  b += dppmov<0x141,0xf, 0xf>(b);  // half-row mirror
    a += dppmov<0x140,0xf, 0xf>(a);  b += dppmov<0x140,0xf, 0xf>(b);  // row mirror
    a += dppmov<0x142,0xa, 0xf>(a);  b += dppmov<0x142,0xa, 0xf>(b);  // row_bcast15
    a += dppmov<0x143,0xc, 0xf>(a);  b += dppmov<0x143,0xc, 0xf>(b);  // row_bcast31
    a = rdlane63(a);                 b = rdlane63(b);
}

// Pre-scaled ELU-dot step (same per-lane arithmetic as round 6, packed where
// v_pk_fma_f32 exists):  p' = pk_fma(wy', y, u');  e = exp2(p');
// z = pk_fma(e, L2E, -L2E);  m = med3(p', z, 0) = L2E*elu(p);
// acc = pk_fma(w2', m, acc)  with w2' = w2*ln2.
__device__ __forceinline__ void mlp_joint(
    const f2 (&wy)[KPL], const f2 (&u)[KPL], const f2 (&w2)[KPL],
    float y, float dbias, float vbias, float& dout, float& vout)
{
    const f2 yv   = {y, y};
    const f2 l2e  = {L2E, L2E};
    const f2 nl2e = {-L2E, -L2E};
    f2 acc0 = {0.f, 0.f}, acc1 = {0.f, 0.f};
#pragma unroll
    for (int k = 0; k < KPL; k += 2) {
        f2 p0 = __builtin_elementwise_fma(wy[k],     yv, u[k]);      // v_pk_fma_f32
        f2 p1 = __builtin_elementwise_fma(wy[k + 1], yv, u[k + 1]);
        f2 e0, e1;
        e0.x = __builtin_amdgcn_exp2f(p0.x);  e0.y = __builtin_amdgcn_exp2f(p0.y);
        e1.x = __builtin_amdgcn_exp2f(p1.x);  e1.y = __builtin_amdgcn_exp2f(p1.y);
        f2 z0 = __builtin_elementwise_fma(e0, l2e, nl2e);            // v_pk_fma_f32
        f2 z1 = __builtin_elementwise_fma(e1, l2e, nl2e);
        f2 m0, m1;
        m0.x = __builtin_amdgcn_fmed3f(p0.x, z0.x, 0.f);
        m0.y = __builtin_amdgcn_fmed3f(p0.y, z0.y, 0.f);
        m1.x = __builtin_amdgcn_fmed3f(p1.x, z1.x, 0.f);
        m1.y = __builtin_amdgcn_fmed3f(p1.y, z1.y, 0.f);
        acc0 = __builtin_elementwise_fma(w2[k],     m0, acc0);       // v_pk_fma_f32
        acc1 = __builtin_elementwise_fma(w2[k + 1], m1, acc1);
    }
    float a = acc0.x + acc1.x;
    float b = acc0.y + acc1.y;
    wred2(a, b);
    dout = a + dbias; vout = b + vbias;
}

__global__ __launch_bounds__(256, 4) void rmodel_kernel(
    const float* __restrict__ X, const float* __restrict__ Y,
    const float* __restrict__ de_W1, const float* __restrict__ de_b1,
    const float* __restrict__ de_W2, const float* __restrict__ de_b2,
    const float* __restrict__ val_W1, const float* __restrict__ val_b1,
    const float* __restrict__ val_W2, const float* __restrict__ val_b2,
    float* __restrict__ out, int n)
{
    const int wid  = threadIdx.x >> 6;
    const int lane = threadIdx.x & 63;
    const int gw   = blockIdx.x * 4 + wid;   // global wave id
    const int GW   = NBLK * 4;               // total resident waves

    const float db2 = de_b2[0];
    const float vb2 = val_b2[0];

    float* __restrict__ yout = out;                       // [NMAX+1][n]
    float* __restrict__ vout = out + (size_t)(NMAX + 1) * n;

    // persistent waves: each wave strides over samples
    for (int b = gw; b < n; b += GW) {
        f2 wy[KPL], u[KPL], w2[KPL];         // .x = de-MLP, .y = val-MLP

        const float x  = X[b];
        const float y0 = Y[b];

#pragma unroll
        for (int k = 0; k < KPL; ++k) {
            const int h = k * 64 + lane;
            float2 w1d = reinterpret_cast<const float2*>(de_W1)[h];
            float2 w1v = reinterpret_cast<const float2*>(val_W1)[h];
            wy[k] = (f2){w1d.y * L2E, w1v.y * L2E};
            u[k]  = (f2){fmaf(w1d.x, x, de_b1[h]) * L2E,
                         fmaf(w1v.x, x, val_b1[h]) * L2E};
            w2[k] = (f2){de_W2[h] * LN2, val_W2[h] * LN2};
        }

        // ---- pipelined chain: each step jointly computes de(y_k) and val(y_k) ----
        float d, v;
        mlp_joint(wy, u, w2, y0, db2, vb2, d, v);         // de(y0), v0
        if (lane == 0) { yout[b] = y0; vout[b] = v; }

        float y     = y0 + d;     // y1
        float vprev = v;          // v0
        float yfin  = y0, vfin = v;
        int   kend  = NMAX;       // last row actually computed

        float* yp = yout + b;
        float* vp = vout + b;
        for (int k = 1; k <= NMAX; ++k) {
            yp += n; vp += n;
            float dk, vk;
            mlp_joint(wy, u, w2, y, db2, vb2, dk, vk);
            if (lane == 0) { *yp = y; *vp = vk; }
            yfin = y; vfin = vk;
            if (k >= 2 && vk >= vprev) { kend = k; break; }  // ref: i>0 && v_new >= v_prev
            vprev = vk;
            y += dk;              // speculative de-eval consumed only on continue
        }

        // ---- frozen rows: lanes store in parallel ----
        const int r = kend + 1 + lane;
        if (r <= NMAX) {
            yout[(size_t)r * n + b] = yfin;
            vout[(size_t)r * n + b] = vfin;
        }
    }
}

extern "C" void kernel_launch(void* const* d_in, const int* in_sizes, int n_in,
                              void* d_out, int out_size, void* d_ws, size_t ws_size,
                              hipStream_t stream) {
    const float* X      = (const float*)d_in[0];
    const float* Y      = (const float*)d_in[1];
    const float* de_W1  = (const float*)d_in[2];
    const float* de_b1  = (const float*)d_in[3];
    const float* de_W2  = (const float*)d_in[4];
    const float* de_b2  = (const float*)d_in[5];
    const float* val_W1 = (const float*)d_in[6];
    const float* val_b1 = (const float*)d_in[7];
    const float* val_W2 = (const float*)d_in[8];
    const float* val_b2 = (const float*)d_in[9];
    float* out = (float*)d_out;

    const int n = in_sizes[0];               // 16384 samples
    dim3 block(256);                          // 4 waves/block
    dim3 grid(NBLK);                          // persistent: 4 blocks/CU
    hipLaunchKernelGGL(rmodel_kernel, grid, block, 0, stream,
                       X, Y, de_W1, de_b1, de_W2, de_b2,
                       val_W1, val_b1, val_W2, val_b2, out, n);
}

// Round 8
// 69.463 us; speedup vs baseline: 1.2230x; 1.2230x over previous
//
#include <hip/hip_runtime.h>

#define NMAX 10
#define KPL  16          // hidden units per lane (1024 / 64)
#define L2E  1.4426950408889634f
#define LN2  0.6931471805599453f

typedef float f2 __attribute__((ext_vector_type(2)));

// ---------- DPP cross-lane sum (VALU pipe only) ----------
template<int CTRL, int RMASK, int BMASK>
__device__ __forceinline__ float dppmov(float v) {
    return __int_as_float(__builtin_amdgcn_update_dpp(
        0, __float_as_int(v), CTRL, RMASK, BMASK, true));
}
__device__ __forceinline__ float rdlane63(float v) {
    return __int_as_float(__builtin_amdgcn_readlane(__float_as_int(v), 63));
}

// two independent wave64 sums -> uniform scalars (2 chains for ILP)
__device__ __forceinline__ void wred2(float& a, float& b) {
    a += dppmov<0xB1, 0xf, 0xf>(a);  b += dppmov<0xB1, 0xf, 0xf>(b);  // quad xor1
    a += dppmov<0x4E, 0xf, 0xf>(a);  b += dppmov<0x4E, 0xf, 0xf>(b);  // quad xor2
    a += dppmov<0x141,0xf, 0xf>(a);  b += dppmov<0x141,0xf, 0xf>(b);  // half-row mirror
    a += dppmov<0x140,0xf, 0xf>(a);  b += dppmov<0x140,0xf, 0xf>(b);  // row mirror
    a += dppmov<0x142,0xa, 0xf>(a);  b += dppmov<0x142,0xa, 0xf>(b);  // row_bcast15
    a += dppmov<0x143,0xc, 0xf>(a);  b += dppmov<0x143,0xc, 0xf>(b);  // row_bcast31
    a = rdlane63(a);                 b = rdlane63(b);
}

// Pre-scaled ELU-dot step, fully packed where v_pk_fma_f32 exists:
//   p' = pk_fma(wy', y, u');  e = exp2(p') (scalar trans x2);
//   z  = pk_fma(e, L2E, -L2E);  m = med3(p', z, 0) = L2E*elu(p) (scalar med3);
//   acc = pk_fma(w2', m, acc)  with wy' = L2E*wy, u' = L2E*u, w2' = w2*ln2.
// Identical per-lane arithmetic to round 6 (bit-exact outputs).
__device__ __forceinline__ void mlp_joint(
    const f2 (&wy)[KPL], const f2 (&u)[KPL], const f2 (&w2)[KPL],
    float y, float dbias, float vbias, float& dout, float& vout)
{
    const f2 yv   = {y, y};
    const f2 l2e  = {L2E, L2E};
    const f2 nl2e = {-L2E, -L2E};
    f2 acc0 = {0.f, 0.f}, acc1 = {0.f, 0.f};
#pragma unroll
    for (int k = 0; k < KPL; k += 2) {
        f2 p0 = __builtin_elementwise_fma(wy[k],     yv, u[k]);      // v_pk_fma_f32
        f2 p1 = __builtin_elementwise_fma(wy[k + 1], yv, u[k + 1]);
        f2 e0, e1;
        e0.x = __builtin_amdgcn_exp2f(p0.x);  e0.y = __builtin_amdgcn_exp2f(p0.y);
        e1.x = __builtin_amdgcn_exp2f(p1.x);  e1.y = __builtin_amdgcn_exp2f(p1.y);
        f2 z0 = __builtin_elementwise_fma(e0, l2e, nl2e);            // v_pk_fma_f32
        f2 z1 = __builtin_elementwise_fma(e1, l2e, nl2e);
        f2 m0, m1;
        m0.x = __builtin_amdgcn_fmed3f(p0.x, z0.x, 0.f);
        m0.y = __builtin_amdgcn_fmed3f(p0.y, z0.y, 0.f);
        m1.x = __builtin_amdgcn_fmed3f(p1.x, z1.x, 0.f);
        m1.y = __builtin_amdgcn_fmed3f(p1.y, z1.y, 0.f);
        acc0 = __builtin_elementwise_fma(w2[k],     m0, acc0);       // v_pk_fma_f32
        acc1 = __builtin_elementwise_fma(w2[k + 1], m1, acc1);
    }
    float a = acc0.x + acc1.x;
    float b = acc0.y + acc1.y;
    wred2(a, b);
    dout = a + dbias; vout = b + vbias;
}

__global__ __launch_bounds__(256) void rmodel_kernel(
    const float* __restrict__ X, const float* __restrict__ Y,
    const float* __restrict__ de_W1, const float* __restrict__ de_b1,
    const float* __restrict__ de_W2, const float* __restrict__ de_b2,
    const float* __restrict__ val_W1, const float* __restrict__ val_b1,
    const float* __restrict__ val_W2, const float* __restrict__ val_b2,
    float* __restrict__ out, int n)
{
    const int wid  = threadIdx.x >> 6;
    const int lane = threadIdx.x & 63;
    const int b    = blockIdx.x * 4 + wid;   // 4 consecutive samples per block
    if (b >= n) return;

    f2 wy[KPL], u[KPL], w2[KPL];             // .x = de-MLP, .y = val-MLP

    const float x  = X[b];
    const float y0 = Y[b];

#pragma unroll
    for (int k = 0; k < KPL; ++k) {
        const int h = k * 64 + lane;
        float2 w1d = reinterpret_cast<const float2*>(de_W1)[h];
        float2 w1v = reinterpret_cast<const float2*>(val_W1)[h];
        wy[k] = (f2){w1d.y * L2E, w1v.y * L2E};
        u[k]  = (f2){fmaf(w1d.x, x, de_b1[h]) * L2E,
                     fmaf(w1v.x, x, val_b1[h]) * L2E};
        w2[k] = (f2){de_W2[h] * LN2, val_W2[h] * LN2};
    }
    const float db2 = de_b2[0];
    const float vb2 = val_b2[0];

    float* __restrict__ yout = out;                       // [NMAX+1][n]
    float* __restrict__ vout = out + (size_t)(NMAX + 1) * n;

    // ---- pipelined chain: each step jointly computes de(y_k) and val(y_k) ----
    float d, v;
    mlp_joint(wy, u, w2, y0, db2, vb2, d, v);             // de(y0), v0
    if (lane == 0) { yout[b] = y0; vout[b] = v; }

    float y     = y0 + d;     // y1
    float vprev = v;          // v0
    float yfin  = y0, vfin = v;
    int   kend  = NMAX;       // last row actually computed

    float* yp = yout + b;
    float* vp = vout + b;
    for (int k = 1; k <= NMAX; ++k) {
        yp += n; vp += n;
        float dk, vk;
        mlp_joint(wy, u, w2, y, db2, vb2, dk, vk);
        if (lane == 0) { *yp = y; *vp = vk; }
        yfin = y; vfin = vk;
        if (k >= 2 && vk >= vprev) { kend = k; break; }   // ref: break when i>0 && v_new >= v_prev
        vprev = vk;
        y += dk;               // speculative de-eval consumed only on continue
    }

    // ---- frozen rows: lanes store in parallel ----
    const int r = kend + 1 + lane;
    if (r <= NMAX) {
        yout[(size_t)r * n + b] = yfin;
        vout[(size_t)r * n + b] = vfin;
    }
}

extern "C" void kernel_launch(void* const* d_in, const int* in_sizes, int n_in,
                              void* d_out, int out_size, void* d_ws, size_t ws_size,
                              hipStream_t stream) {
    const float* X      = (const float*)d_in[0];
    const float* Y      = (const float*)d_in[1];
    const float* de_W1  = (const float*)d_in[2];
    const float* de_b1  = (const float*)d_in[3];
    const float* de_W2  = (const float*)d_in[4];
    const float* de_b2  = (const float*)d_in[5];
    const float* val_W1 = (const float*)d_in[6];
    const float* val_b1 = (const float*)d_in[7];
    const float* val_W2 = (const float*)d_in[8];
    const float* val_b2 = (const float*)d_in[9];
    float* out = (float*)d_out;

    const int n = in_sizes[0];               // 16384 samples
    dim3 block(256);                          // 4 waves/block, 1 wave = 1 sample
    dim3 grid((n + 3) / 4);
    hipLaunchKernelGGL(rmodel_kernel, grid, block, 0, stream,
                       X, Y, de_W1, de_b1, de_W2, de_b2,
                       val_W1, val_b1, val_W2, val_b2, out, n);
}

// Round 9
// 68.760 us; speedup vs baseline: 1.2355x; 1.0102x over previous
//
#include <hip/hip_runtime.h>

#define NMAX 10
#define KPL  16          // hidden units per lane (1024 / 64)
#define L2E  1.4426950408889634f
#define LN2  0.6931471805599453f

typedef float f2 __attribute__((ext_vector_type(2)));

// ---------- DPP cross-lane sum (VALU pipe only) ----------
template<int CTRL, int RMASK, int BMASK>
__device__ __forceinline__ float dppmov(float v) {
    return __int_as_float(__builtin_amdgcn_update_dpp(
        0, __float_as_int(v), CTRL, RMASK, BMASK, true));
}
__device__ __forceinline__ float rdlane63(float v) {
    return __int_as_float(__builtin_amdgcn_readlane(__float_as_int(v), 63));
}

// two independent wave64 sums -> uniform scalars (2 chains for ILP)
__device__ __forceinline__ void wred2(float& a, float& b) {
    a += dppmov<0xB1, 0xf, 0xf>(a);  b += dppmov<0xB1, 0xf, 0xf>(b);  // quad xor1
    a += dppmov<0x4E, 0xf, 0xf>(a);  b += dppmov<0x4E, 0xf, 0xf>(b);  // quad xor2
    a += dppmov<0x141,0xf, 0xf>(a);  b += dppmov<0x141,0xf, 0xf>(b);  // half-row mirror
    a += dppmov<0x140,0xf, 0xf>(a);  b += dppmov<0x140,0xf, 0xf>(b);  // row mirror
    a += dppmov<0x142,0xa, 0xf>(a);  b += dppmov<0x142,0xa, 0xf>(b);  // row_bcast15
    a += dppmov<0x143,0xc, 0xf>(a);  b += dppmov<0x143,0xc, 0xf>(b);  // row_bcast31
    a = rdlane63(a);                 b = rdlane63(b);
}

// Pre-scaled ELU-dot step, fully packed where v_pk_fma_f32 exists:
//   p' = pk_fma(wy', y, u');  e = exp2(p') (scalar trans x2);
//   z  = pk_fma(e, L2E, -L2E);  m = med3(p', z, 0) = L2E*elu(p) (scalar med3);
//   acc = pk_fma(w2', m, acc)  with wy' = L2E*wy, u' = L2E*u, w2' = w2*ln2.
__device__ __forceinline__ void mlp_joint(
    const f2 (&wy)[KPL], const f2 (&u)[KPL], const f2 (&w2)[KPL],
    float y, float dbias, float vbias, float& dout, float& vout)
{
    const f2 yv   = {y, y};
    const f2 l2e  = {L2E, L2E};
    const f2 nl2e = {-L2E, -L2E};
    f2 acc0 = {0.f, 0.f}, acc1 = {0.f, 0.f};
#pragma unroll
    for (int k = 0; k < KPL; k += 2) {
        f2 p0 = __builtin_elementwise_fma(wy[k],     yv, u[k]);      // v_pk_fma_f32
        f2 p1 = __builtin_elementwise_fma(wy[k + 1], yv, u[k + 1]);
        f2 e0, e1;
        e0.x = __builtin_amdgcn_exp2f(p0.x);  e0.y = __builtin_amdgcn_exp2f(p0.y);
        e1.x = __builtin_amdgcn_exp2f(p1.x);  e1.y = __builtin_amdgcn_exp2f(p1.y);
        f2 z0 = __builtin_elementwise_fma(e0, l2e, nl2e);            // v_pk_fma_f32
        f2 z1 = __builtin_elementwise_fma(e1, l2e, nl2e);
        f2 m0, m1;
        m0.x = __builtin_amdgcn_fmed3f(p0.x, z0.x, 0.f);
        m0.y = __builtin_amdgcn_fmed3f(p0.y, z0.y, 0.f);
        m1.x = __builtin_amdgcn_fmed3f(p1.x, z1.x, 0.f);
        m1.y = __builtin_amdgcn_fmed3f(p1.y, z1.y, 0.f);
        acc0 = __builtin_elementwise_fma(w2[k],     m0, acc0);       // v_pk_fma_f32
        acc1 = __builtin_elementwise_fma(w2[k + 1], m1, acc1);
    }
    float a = acc0.x + acc1.x;
    float b = acc0.y + acc1.y;
    wred2(a, b);
    dout = a + dbias; vout = b + vbias;
}

// 1-wave workgroups: waves retire independently -> no block-granularity
// straggler hold; register cap (4 waves/SIMD) becomes the only occupancy limit.
__global__ __launch_bounds__(64) void rmodel_kernel(
    const float* __restrict__ X, const float* __restrict__ Y,
    const float* __restrict__ de_W1, const float* __restrict__ de_b1,
    const float* __restrict__ de_W2, const float* __restrict__ de_b2,
    const float* __restrict__ val_W1, const float* __restrict__ val_b1,
    const float* __restrict__ val_W2, const float* __restrict__ val_b2,
    float* __restrict__ out, int n)
{
    const int lane = threadIdx.x & 63;
    const int b    = blockIdx.x;             // one wave = one sample
    if (b >= n) return;

    f2 wy[KPL], u[KPL], w2[KPL];             // .x = de-MLP, .y = val-MLP

    const float x  = X[b];
    const float y0 = Y[b];

#pragma unroll
    for (int k = 0; k < KPL; ++k) {
        const int h = k * 64 + lane;
        float2 w1d = reinterpret_cast<const float2*>(de_W1)[h];
        float2 w1v = reinterpret_cast<const float2*>(val_W1)[h];
        wy[k] = (f2){w1d.y * L2E, w1v.y * L2E};
        u[k]  = (f2){fmaf(w1d.x, x, de_b1[h]) * L2E,
                     fmaf(w1v.x, x, val_b1[h]) * L2E};
        w2[k] = (f2){de_W2[h] * LN2, val_W2[h] * LN2};
    }
    const float db2 = de_b2[0];
    const float vb2 = val_b2[0];

    float* __restrict__ yout = out;                       // [NMAX+1][n]
    float* __restrict__ vout = out + (size_t)(NMAX + 1) * n;

    // ---- pipelined chain: each step jointly computes de(y_k) and val(y_k) ----
    float d, v;
    mlp_joint(wy, u, w2, y0, db2, vb2, d, v);             // de(y0), v0
    if (lane == 0) { yout[b] = y0; vout[b] = v; }

    float y     = y0 + d;     // y1
    float vprev = v;          // v0
    float yfin  = y0, vfin = v;
    int   kend  = NMAX;       // last row actually computed

    float* yp = yout + b;
    float* vp = vout + b;
    for (int k = 1; k <= NMAX; ++k) {
        yp += n; vp += n;
        float dk, vk;
        mlp_joint(wy, u, w2, y, db2, vb2, dk, vk);
        if (lane == 0) { *yp = y; *vp = vk; }
        yfin = y; vfin = vk;
        if (k >= 2 && vk >= vprev) { kend = k; break; }   // ref: break when i>0 && v_new >= v_prev
        vprev = vk;
        y += dk;               // speculative de-eval consumed only on continue
    }

    // ---- frozen rows: lanes store in parallel ----
    const int r = kend + 1 + lane;
    if (r <= NMAX) {
        yout[(size_t)r * n + b] = yfin;
        vout[(size_t)r * n + b] = vfin;
    }
}

extern "C" void kernel_launch(void* const* d_in, const int* in_sizes, int n_in,
                              void* d_out, int out_size, void* d_ws, size_t ws_size,
                              hipStream_t stream) {
    const float* X      = (const float*)d_in[0];
    const float* Y      = (const float*)d_in[1];
    const float* de_W1  = (const float*)d_in[2];
    const float* de_b1  = (const float*)d_in[3];
    const float* de_W2  = (const float*)d_in[4];
    const float* de_b2  = (const float*)d_in[5];
    const float* val_W1 = (const float*)d_in[6];
    const float* val_b1 = (const float*)d_in[7];
    const float* val_W2 = (const float*)d_in[8];
    const float* val_b2 = (const float*)d_in[9];
    float* out = (float*)d_out;

    const int n = in_sizes[0];               // 16384 samples
    dim3 block(64);                           // 1 wave per workgroup
    dim3 grid(n);
    hipLaunchKernelGGL(rmodel_kernel, grid, block, 0, stream,
                       X, Y, de_W1, de_b1, de_W2, de_b2,
                       val_W1, val_b1, val_W2, val_b2, out, n);
}

// Round 10
// 65.904 us; speedup vs baseline: 1.2890x; 1.0433x over previous
//
#include <hip/hip_runtime.h>

#define NMAX 10
#define KPL  16          // hidden units per lane (1024 / 64)
#define L2E  1.4426950408889634f
#define LN2  0.6931471805599453f

typedef float f2 __attribute__((ext_vector_type(2)));

// ---------- DPP cross-lane sum (VALU pipe only) ----------
template<int CTRL, int RMASK, int BMASK>
__device__ __forceinline__ float dppmov(float v) {
    return __int_as_float(__builtin_amdgcn_update_dpp(
        0, __float_as_int(v), CTRL, RMASK, BMASK, true));
}
__device__ __forceinline__ float rdlane63(float v) {
    return __int_as_float(__builtin_amdgcn_readlane(__float_as_int(v), 63));
}

// two independent wave64 sums -> uniform scalars (2 chains for ILP)
__device__ __forceinline__ void wred2(float& a, float& b) {
    a += dppmov<0xB1, 0xf, 0xf>(a);  b += dppmov<0xB1, 0xf, 0xf>(b);  // quad xor1
    a += dppmov<0x4E, 0xf, 0xf>(a);  b += dppmov<0x4E, 0xf, 0xf>(b);  // quad xor2
    a += dppmov<0x141,0xf, 0xf>(a);  b += dppmov<0x141,0xf, 0xf>(b);  // half-row mirror
    a += dppmov<0x140,0xf, 0xf>(a);  b += dppmov<0x140,0xf, 0xf>(b);  // row mirror
    a += dppmov<0x142,0xa, 0xf>(a);  b += dppmov<0x142,0xa, 0xf>(b);  // row_bcast15
    a += dppmov<0x143,0xc, 0xf>(a);  b += dppmov<0x143,0xc, 0xf>(b);  // row_bcast31
    a = rdlane63(a);                 b = rdlane63(b);
}

// Pre-scaled ELU-dot step; weights streamed from LDS (ds_read_b128/unit),
// only per-sample u[] lives in registers.  Same per-lane arithmetic as r8:
//   p' = pk_fma(wy', y, u');  e = exp2(p');  z = pk_fma(e, L2E, -L2E);
//   m = med3(p', z, 0) = L2E*elu(p);  acc = pk_fma(w2', m, acc).
__device__ __forceinline__ void mlp_joint(
    const float4* __restrict__ wl,           // &wlds[lane], stride 64 per k
    const f2 (&u)[KPL],
    float y, float dbias, float vbias, float& dout, float& vout)
{
    const f2 yv   = {y, y};
    const f2 l2e  = {L2E, L2E};
    const f2 nl2e = {-L2E, -L2E};
    f2 acc0 = {0.f, 0.f}, acc1 = {0.f, 0.f};
#pragma unroll
    for (int k = 0; k < KPL; k += 2) {
        const float4 wa = wl[k * 64];        // {wy_d, wy_v, w2_d, w2_v}
        const float4 wb = wl[(k + 1) * 64];
        f2 wya = {wa.x, wa.y}, w2a = {wa.z, wa.w};
        f2 wyb = {wb.x, wb.y}, w2b = {wb.z, wb.w};
        f2 p0 = __builtin_elementwise_fma(wya, yv, u[k]);            // v_pk_fma_f32
        f2 p1 = __builtin_elementwise_fma(wyb, yv, u[k + 1]);
        f2 e0, e1;
        e0.x = __builtin_amdgcn_exp2f(p0.x);  e0.y = __builtin_amdgcn_exp2f(p0.y);
        e1.x = __builtin_amdgcn_exp2f(p1.x);  e1.y = __builtin_amdgcn_exp2f(p1.y);
        f2 z0 = __builtin_elementwise_fma(e0, l2e, nl2e);            // v_pk_fma_f32
        f2 z1 = __builtin_elementwise_fma(e1, l2e, nl2e);
        f2 m0, m1;
        m0.x = __builtin_amdgcn_fmed3f(p0.x, z0.x, 0.f);
        m0.y = __builtin_amdgcn_fmed3f(p0.y, z0.y, 0.f);
        m1.x = __builtin_amdgcn_fmed3f(p1.x, z1.x, 0.f);
        m1.y = __builtin_amdgcn_fmed3f(p1.y, z1.y, 0.f);
        acc0 = __builtin_elementwise_fma(w2a, m0, acc0);             // v_pk_fma_f32
        acc1 = __builtin_elementwise_fma(w2b, m1, acc1);
    }
    float a = acc0.x + acc1.x;
    float b = acc0.y + acc1.y;
    wred2(a, b);
    dout = a + dbias; vout = b + vbias;
}

__global__ __launch_bounds__(256) void rmodel_kernel(
    const float* __restrict__ X, const float* __restrict__ Y,
    const float* __restrict__ de_W1, const float* __restrict__ de_b1,
    const float* __restrict__ de_W2, const float* __restrict__ de_b2,
    const float* __restrict__ val_W1, const float* __restrict__ val_b1,
    const float* __restrict__ val_W2, const float* __restrict__ val_b2,
    float* __restrict__ out, int n)
{
    __shared__ float4 wlds[KPL * 64];        // 16 KB: {wy_d, wy_v, w2_d, w2_v}[h]

    const int tid  = threadIdx.x;
    const int wid  = tid >> 6;
    const int lane = tid & 63;
    const int b    = blockIdx.x * 4 + wid;   // 4 consecutive samples per block

    // ---- cooperative LDS fill: sample-invariant pre-scaled weights ----
#pragma unroll
    for (int i = 0; i < 4; ++i) {
        const int h = tid + i * 256;
        float2 w1d = reinterpret_cast<const float2*>(de_W1)[h];
        float2 w1v = reinterpret_cast<const float2*>(val_W1)[h];
        wlds[h] = make_float4(w1d.y * L2E, w1v.y * L2E,
                              de_W2[h] * LN2, val_W2[h] * LN2);
    }
    __syncthreads();

    if (b >= n) return;

    // ---- per-sample state: only u[] (32 VGPRs) ----
    f2 u[KPL];
    const float x  = X[b];
    const float y0 = Y[b];
#pragma unroll
    for (int k = 0; k < KPL; ++k) {
        const int h = k * 64 + lane;
        float2 w1d = reinterpret_cast<const float2*>(de_W1)[h];
        float2 w1v = reinterpret_cast<const float2*>(val_W1)[h];
        u[k] = (f2){fmaf(w1d.x, x, de_b1[h]) * L2E,
                    fmaf(w1v.x, x, val_b1[h]) * L2E};
    }
    const float db2 = de_b2[0];
    const float vb2 = val_b2[0];
    const float4* wl = &wlds[lane];

    float* __restrict__ yout = out;                       // [NMAX+1][n]
    float* __restrict__ vout = out + (size_t)(NMAX + 1) * n;

    // ---- pipelined chain: each step jointly computes de(y_k) and val(y_k) ----
    float d, v;
    mlp_joint(wl, u, y0, db2, vb2, d, v);                 // de(y0), v0
    if (lane == 0) { yout[b] = y0; vout[b] = v; }

    float y     = y0 + d;     // y1
    float vprev = v;          // v0
    float yfin  = y0, vfin = v;
    int   kend  = NMAX;       // last row actually computed

    float* yp = yout + b;
    float* vp = vout + b;
    for (int k = 1; k <= NMAX; ++k) {
        yp += n; vp += n;
        float dk, vk;
        mlp_joint(wl, u, y, db2, vb2, dk, vk);
        if (lane == 0) { *yp = y; *vp = vk; }
        yfin = y; vfin = vk;
        if (k >= 2 && vk >= vprev) { kend = k; break; }   // ref: break when i>0 && v_new >= v_prev
        vprev = vk;
        y += dk;               // speculative de-eval consumed only on continue
    }

    // ---- frozen rows: lanes store in parallel ----
    const int r = kend + 1 + lane;
    if (r <= NMAX) {
        yout[(size_t)r * n + b] = yfin;
        vout[(size_t)r * n + b] = vfin;
    }
}

extern "C" void kernel_launch(void* const* d_in, const int* in_sizes, int n_in,
                              void* d_out, int out_size, void* d_ws, size_t ws_size,
                              hipStream_t stream) {
    const float* X      = (const float*)d_in[0];
    const float* Y      = (const float*)d_in[1];
    const float* de_W1  = (const float*)d_in[2];
    const float* de_b1  = (const float*)d_in[3];
    const float* de_W2  = (const float*)d_in[4];
    const float* de_b2  = (const float*)d_in[5];
    const float* val_W1 = (const float*)d_in[6];
    const float* val_b1 = (const float*)d_in[7];
    const float* val_W2 = (const float*)d_in[8];
    const float* val_b2 = (const float*)d_in[9];
    float* out = (float*)d_out;

    const int n = in_sizes[0];               // 16384 samples
    dim3 block(256);                          // 4 waves/block, 1 wave = 1 sample
    dim3 grid((n + 3) / 4);
    hipLaunchKernelGGL(rmodel_kernel, grid, block, 0, stream,
                       X, Y, de_W1, de_b1, de_W2, de_b2,
                       val_W1, val_b1, val_W2, val_b2, out, n);
}

// Round 11
// 65.343 us; speedup vs baseline: 1.3001x; 1.0086x over previous
//
#include <hip/hip_runtime.h>

#define NMAX 10
#define KPL  16          // hidden units per lane (1024 / 64)
#define L2E  1.4426950408889634f
#define LN2  0.6931471805599453f

typedef float f2 __attribute__((ext_vector_type(2)));

// ---------- DPP cross-lane sum (VALU pipe only) ----------
template<int CTRL, int RMASK, int BMASK>
__device__ __forceinline__ float dppmov(float v) {
    return __int_as_float(__builtin_amdgcn_update_dpp(
        0, __float_as_int(v), CTRL, RMASK, BMASK, true));
}
__device__ __forceinline__ float rdlane63(float v) {
    return __int_as_float(__builtin_amdgcn_readlane(__float_as_int(v), 63));
}

#define WRED_STAGE(CTRL, RM) \
    a += dppmov<CTRL, RM, 0xf>(a);  b += dppmov<CTRL, RM, 0xf>(b);

// two independent wave64 sums -> uniform scalars
__device__ __forceinline__ void wred2(float& a, float& b) {
    WRED_STAGE(0xB1, 0xf)   // quad xor1
    WRED_STAGE(0x4E, 0xf)   // quad xor2
    WRED_STAGE(0x141,0xf)   // half-row mirror (xor4)
    WRED_STAGE(0x140,0xf)   // row mirror (xor8)
    WRED_STAGE(0x142,0xa)   // row_bcast15 -> rows 1,3
    WRED_STAGE(0x143,0xc)   // row_bcast31 -> rows 2,3
    a = rdlane63(a);  b = rdlane63(b);
}

#define WRED4_STAGE(CTRL, RM) \
    a += dppmov<CTRL, RM, 0xf>(a);  b += dppmov<CTRL, RM, 0xf>(b); \
    c += dppmov<CTRL, RM, 0xf>(c);  d += dppmov<CTRL, RM, 0xf>(d);

// four independent wave64 sums (2 samples x de/val) -> uniform scalars
__device__ __forceinline__ void wred4(float& a, float& b, float& c, float& d) {
    WRED4_STAGE(0xB1, 0xf)
    WRED4_STAGE(0x4E, 0xf)
    WRED4_STAGE(0x141,0xf)
    WRED4_STAGE(0x140,0xf)
    WRED4_STAGE(0x142,0xa)
    WRED4_STAGE(0x143,0xc)
    a = rdlane63(a);  b = rdlane63(b);  c = rdlane63(c);  d = rdlane63(d);
}

// One hidden-unit pair (de+val packed in f2), pre-scaled ELU-dot step:
//   p' = pk_fma(wy', y, u');  e = exp2(p');  z = pk_fma(e, L2E, -L2E);
//   m = med3(p', z, 0) = L2E*elu(p);  acc = pk_fma(w2', m, acc).
__device__ __forceinline__ void unit_step(const float4 w, const f2 u, const f2 yv, f2& acc) {
    const f2 l2e  = {L2E, L2E};
    const f2 nl2e = {-L2E, -L2E};
    f2 wy = {w.x, w.y}, w2 = {w.z, w.w};
    f2 p = __builtin_elementwise_fma(wy, yv, u);     // v_pk_fma_f32
    f2 e;
    e.x = __builtin_amdgcn_exp2f(p.x);  e.y = __builtin_amdgcn_exp2f(p.y);
    f2 z = __builtin_elementwise_fma(e, l2e, nl2e);  // v_pk_fma_f32
    f2 m;
    m.x = __builtin_amdgcn_fmed3f(p.x, z.x, 0.f);
    m.y = __builtin_amdgcn_fmed3f(p.y, z.y, 0.f);
    acc = __builtin_elementwise_fma(w2, m, acc);     // v_pk_fma_f32
}

// joint de+val eval for ONE sample (2 chains) -- tail path, same as round 10
__device__ __forceinline__ void mlp_joint(
    const float4* __restrict__ wl, const f2 (&u)[KPL],
    float y, float dbias, float vbias, float& dout, float& vout)
{
    const f2 yv = {y, y};
    f2 acc0 = {0.f, 0.f}, acc1 = {0.f, 0.f};
#pragma unroll
    for (int k = 0; k < KPL; k += 2) {
        const float4 wa = wl[k * 64];
        const float4 wb = wl[(k + 1) * 64];
        unit_step(wa, u[k],     yv, acc0);
        unit_step(wb, u[k + 1], yv, acc1);
    }
    float a = acc0.x + acc1.x;
    float b = acc0.y + acc1.y;
    wred2(a, b);
    dout = a + dbias; vout = b + vbias;
}

// joint de+val eval for TWO samples (4 independent chains; weights read once)
__device__ __forceinline__ void mlp_joint2(
    const float4* __restrict__ wl,
    const f2 (&uA)[KPL], const f2 (&uB)[KPL],
    float yA, float yB, float dbias, float vbias,
    float& dA, float& vA, float& dB, float& vB)
{
    const f2 yvA = {yA, yA}, yvB = {yB, yB};
    f2 aA0 = {0.f, 0.f}, aA1 = {0.f, 0.f};
    f2 aB0 = {0.f, 0.f}, aB1 = {0.f, 0.f};
#pragma unroll
    for (int k = 0; k < KPL; k += 2) {
        const float4 wa = wl[k * 64];        // shared by both samples
        const float4 wb = wl[(k + 1) * 64];
        unit_step(wa, uA[k],     yvA, aA0);
        unit_step(wa, uB[k],     yvB, aB0);
        unit_step(wb, uA[k + 1], yvA, aA1);
        unit_step(wb, uB[k + 1], yvB, aB1);
    }
    float a = aA0.x + aA1.x;   // de  A
    float b = aA0.y + aA1.y;   // val A
    float c = aB0.x + aB1.x;   // de  B
    float d = aB0.y + aB1.y;   // val B
    wred4(a, b, c, d);
    dA = a + dbias; vA = b + vbias;
    dB = c + dbias; vB = d + vbias;
}

__global__ __launch_bounds__(256) void rmodel_kernel(
    const float* __restrict__ X, const float* __restrict__ Y,
    const float* __restrict__ de_W1, const float* __restrict__ de_b1,
    const float* __restrict__ de_W2, const float* __restrict__ de_b2,
    const float* __restrict__ val_W1, const float* __restrict__ val_b1,
    const float* __restrict__ val_W2, const float* __restrict__ val_b2,
    float* __restrict__ out, int n)
{
    __shared__ float4 wlds[KPL * 64];        // 16 KB: {wy_d, wy_v, w2_d, w2_v}[h]

    const int tid  = threadIdx.x;
    const int wid  = tid >> 6;
    const int lane = tid & 63;

    // ---- cooperative LDS fill: sample-invariant pre-scaled weights ----
#pragma unroll
    for (int i = 0; i < 4; ++i) {
        const int h = tid + i * 256;
        float2 w1d = reinterpret_cast<const float2*>(de_W1)[h];
        float2 w1v = reinterpret_cast<const float2*>(val_W1)[h];
        wlds[h] = make_float4(w1d.y * L2E, w1v.y * L2E,
                              de_W2[h] * LN2, val_W2[h] * LN2);
    }
    __syncthreads();

    const int p  = blockIdx.x * 4 + wid;     // pair index: one wave = 2 samples
    const int bA = 2 * p;
    if (bA >= n) return;
    const bool hasB = (bA + 1 < n);
    const int bB = hasB ? bA + 1 : bA;

    // ---- per-sample state: u[] only (pre-scaled, x-hoisted) ----
    f2 uA[KPL], uB[KPL];
    const float xA = X[bA], xB = X[bB];
    const float y0A = Y[bA], y0B = Y[bB];
#pragma unroll
    for (int k = 0; k < KPL; ++k) {
        const int h = k * 64 + lane;
        float2 w1d = reinterpret_cast<const float2*>(de_W1)[h];
        float2 w1v = reinterpret_cast<const float2*>(val_W1)[h];
        const float bd = de_b1[h], bv = val_b1[h];
        uA[k] = (f2){fmaf(w1d.x, xA, bd) * L2E, fmaf(w1v.x, xA, bv) * L2E};
        uB[k] = (f2){fmaf(w1d.x, xB, bd) * L2E, fmaf(w1v.x, xB, bv) * L2E};
    }
    const float db2 = de_b2[0];
    const float vb2 = val_b2[0];
    const float4* wl = &wlds[lane];

    float* __restrict__ yout = out;                       // [NMAX+1][n]
    float* __restrict__ vout = out + (size_t)(NMAX + 1) * n;

    // ---- step 0: joint de(y0)+val(y0) for both samples ----
    float dA, vA, dB, vB;
    mlp_joint2(wl, uA, uB, y0A, y0B, db2, vb2, dA, vA, dB, vB);
    if (lane == 0) {
        yout[bA] = y0A; vout[bA] = vA;
        if (hasB) { yout[bB] = y0B; vout[bB] = vB; }
    }

    float yA = y0A + dA, yB = y0B + dB;
    float vpA = vA, vpB = vB;
    float yfinA = y0A, vfinA = vA, yfinB = y0B, vfinB = vB;
    int kendA = NMAX, kendB = NMAX;
    bool actA = true, actB = hasB;
    int k = 1;

    // ---- joint phase: both samples advance in lockstep (4-chain ILP) ----
    while (k <= NMAX && actA && actB) {
        float dkA, vkA, dkB, vkB;
        mlp_joint2(wl, uA, uB, yA, yB, db2, vb2, dkA, vkA, dkB, vkB);
        if (lane == 0) {
            yout[(size_t)k * n + bA] = yA; vout[(size_t)k * n + bA] = vkA;
            yout[(size_t)k * n + bB] = yB; vout[(size_t)k * n + bB] = vkB;
        }
        yfinA = yA; vfinA = vkA; yfinB = yB; vfinB = vkB;
        const bool brkA = (k >= 2) && (vkA >= vpA);   // ref: i>0 && v_new >= v_prev
        const bool brkB = (k >= 2) && (vkB >= vpB);
        vpA = vkA; vpB = vkB;
        if (brkA) { kendA = k; actA = false; } else { yA += dkA; }
        if (brkB) { kendB = k; actB = false; } else { yB += dkB; }
        ++k;
    }
    // ---- tails: at most one sample still active ----
    while (k <= NMAX && actA) {
        float dk, vk;
        mlp_joint(wl, uA, yA, db2, vb2, dk, vk);
        if (lane == 0) {
            yout[(size_t)k * n + bA] = yA; vout[(size_t)k * n + bA] = vk;
        }
        yfinA = yA; vfinA = vk;
        const bool brk = (k >= 2) && (vk >= vpA);
        vpA = vk;
        if (brk) { kendA = k; actA = false; } else { yA += dk; }
        ++k;
    }
    while (k <= NMAX && actB) {
        float dk, vk;
        mlp_joint(wl, uB, yB, db2, vb2, dk, vk);
        if (lane == 0) {
            yout[(size_t)k * n + bB] = yB; vout[(size_t)k * n + bB] = vk;
        }
        yfinB = yB; vfinB = vk;
        const bool brk = (k >= 2) && (vk >= vpB);
        vpB = vk;
        if (brk) { kendB = k; actB = false; } else { yB += dk; }
        ++k;
    }

    // ---- frozen rows: lanes store in parallel ----
    const int rA = kendA + 1 + lane;
    if (rA <= NMAX) {
        yout[(size_t)rA * n + bA] = yfinA;
        vout[(size_t)rA * n + bA] = vfinA;
    }
    if (hasB) {
        const int rB = kendB + 1 + lane;
        if (rB <= NMAX) {
            yout[(size_t)rB * n + bB] = yfinB;
            vout[(size_t)rB * n + bB] = vfinB;
        }
    }
}

extern "C" void kernel_launch(void* const* d_in, const int* in_sizes, int n_in,
                              void* d_out, int out_size, void* d_ws, size_t ws_size,
                              hipStream_t stream) {
    const float* X      = (const float*)d_in[0];
    const float* Y      = (const float*)d_in[1];
    const float* de_W1  = (const float*)d_in[2];
    const float* de_b1  = (const float*)d_in[3];
    const float* de_W2  = (const float*)d_in[4];
    const float* de_b2  = (const float*)d_in[5];
    const float* val_W1 = (const float*)d_in[6];
    const float* val_b1 = (const float*)d_in[7];
    const float* val_W2 = (const float*)d_in[8];
    const float* val_b2 = (const float*)d_in[9];
    float* out = (float*)d_out;

    const int n     = in_sizes[0];           // 16384 samples
    const int pairs = (n + 1) / 2;           // one wave = 2 samples
    dim3 block(256);                          // 4 waves/block = 8 samples/block
    dim3 grid((pairs + 3) / 4);
    hipLaunchKernelGGL(rmodel_kernel, grid, block, 0, stream,
                       X, Y, de_W1, de_b1, de_W2, de_b2,
                       val_W1, val_b1, val_W2, val_b2, out, n);
}

// Round 12
// 65.197 us; speedup vs baseline: 1.3030x; 1.0022x over previous
//
#include <hip/hip_runtime.h>

#define NMAX 10
#define NP   8           // f2 unit-pairs per lane per MLP (16 units = 8 x f2)
#define L2E  1.4426950408889634f
#define LN2  0.6931471805599453f

typedef float f2 __attribute__((ext_vector_type(2)));

// ---------- DPP cross-lane sum (VALU pipe only) ----------
template<int CTRL, int RMASK, int BMASK>
__device__ __forceinline__ float dppmov(float v) {
    return __int_as_float(__builtin_amdgcn_update_dpp(
        0, __float_as_int(v), CTRL, RMASK, BMASK, true));
}
__device__ __forceinline__ float rdlane63(float v) {
    return __int_as_float(__builtin_amdgcn_readlane(__float_as_int(v), 63));
}

// one wave64 sum -> uniform scalar
__device__ __forceinline__ float wred1(float a) {
    a += dppmov<0xB1, 0xf, 0xf>(a);   // quad xor1
    a += dppmov<0x4E, 0xf, 0xf>(a);   // quad xor2
    a += dppmov<0x141,0xf, 0xf>(a);   // half-row mirror (xor4)
    a += dppmov<0x140,0xf, 0xf>(a);   // row mirror (xor8)
    a += dppmov<0x142,0xa, 0xf>(a);   // row_bcast15 -> rows 1,3
    a += dppmov<0x143,0xc, 0xf>(a);   // row_bcast31 -> rows 2,3
    return rdlane63(a);
}

// One f2 unit-pair, pre-scaled ELU-dot step (bit-identical to rounds 8-11):
//   p' = pk_fma(wy', y, u');  e = exp2(p');  z = pk_fma(e, L2E, -L2E);
//   m = med3(p', z, 0) = L2E*elu(p);  acc = pk_fma(w2', m, acc).
__device__ __forceinline__ void unit_step(const f2 wy, const f2 w2,
                                          const f2 u, const f2 yv, f2& acc) {
    const f2 l2e  = {L2E, L2E};
    const f2 nl2e = {-L2E, -L2E};
    f2 p = __builtin_elementwise_fma(wy, yv, u);     // v_pk_fma_f32
    f2 e;
    e.x = __builtin_amdgcn_exp2f(p.x);  e.y = __builtin_amdgcn_exp2f(p.y);
    f2 z = __builtin_elementwise_fma(e, l2e, nl2e);  // v_pk_fma_f32
    f2 m;
    m.x = __builtin_amdgcn_fmed3f(p.x, z.x, 0.f);
    m.y = __builtin_amdgcn_fmed3f(p.y, z.y, 0.f);
    acc = __builtin_elementwise_fma(w2, m, acc);     // v_pk_fma_f32
}

// single-MLP eval: 8 f2 unit-pairs from LDS float4 {wy_lo, wy_hi, w2_lo, w2_hi}
__device__ __forceinline__ float mlp_one(
    const float4* __restrict__ wl,   // &wlds[mlp_base + lane], stride 64/pair
    const f2 (&u)[NP], float y, float bias)
{
    const f2 yv = {y, y};
    f2 acc0 = {0.f, 0.f}, acc1 = {0.f, 0.f};
#pragma unroll
    for (int p = 0; p < NP; p += 2) {
        const float4 wa = wl[p * 64];
        const float4 wb = wl[(p + 1) * 64];
        unit_step((f2){wa.x, wa.y}, (f2){wa.z, wa.w}, u[p],     yv, acc0);
        unit_step((f2){wb.x, wb.y}, (f2){wb.z, wb.w}, u[p + 1], yv, acc1);
    }
    f2 acc = acc0 + acc1;
    return wred1(acc.x + acc.y) + bias;
}

__global__ __launch_bounds__(256) void rmodel_kernel(
    const float* __restrict__ X, const float* __restrict__ Y,
    const float* __restrict__ de_W1, const float* __restrict__ de_b1,
    const float* __restrict__ de_W2, const float* __restrict__ de_b2,
    const float* __restrict__ val_W1, const float* __restrict__ val_b1,
    const float* __restrict__ val_W2, const float* __restrict__ val_b2,
    float* __restrict__ out, int n)
{
    // 16 KB: [0..511] = val-MLP unit-pairs, [512..1023] = de-MLP unit-pairs.
    // entry e = p*64 + lane: units h0 = lane + 128p, h1 = h0 + 64.
    __shared__ float4 wlds[2 * NP * 64];

    const int tid  = threadIdx.x;
    const int wid  = tid >> 6;
    const int lane = tid & 63;

    // ---- cooperative LDS fill: sample-invariant pre-scaled weights ----
#pragma unroll
    for (int i = 0; i < 4; ++i) {
        const int e  = tid + i * 256;        // 0..1023
        const int a  = e >> 9;               // 0 = val, 1 = de
        const int ei = e & 511;
        const int p  = ei >> 6, l = ei & 63;
        const int h0 = l + (p << 7), h1 = h0 + 64;
        const float* W1 = a ? de_W1 : val_W1;
        const float* W2 = a ? de_W2 : val_W2;
        wlds[e] = make_float4(W1[2 * h0 + 1] * L2E, W1[2 * h1 + 1] * L2E,
                              W2[h0] * LN2,         W2[h1] * LN2);
    }
    __syncthreads();

    const int b = blockIdx.x * 4 + wid;      // one wave = one sample
    if (b >= n) return;

    // ---- per-sample state: u[] only (pre-scaled, x-hoisted) ----
    f2 uv[NP], ud[NP];
    const float x  = X[b];
    const float y0 = Y[b];
#pragma unroll
    for (int p = 0; p < NP; ++p) {
        const int h0 = lane + (p << 7), h1 = h0 + 64;
        uv[p] = (f2){fmaf(val_W1[2 * h0], x, val_b1[h0]) * L2E,
                     fmaf(val_W1[2 * h1], x, val_b1[h1]) * L2E};
        ud[p] = (f2){fmaf(de_W1[2 * h0], x, de_b1[h0]) * L2E,
                     fmaf(de_W1[2 * h1], x, de_b1[h1]) * L2E};
    }
    const float db2 = de_b2[0];
    const float vb2 = val_b2[0];
    const float4* wlv = &wlds[lane];         // val-MLP base
    const float4* wld = &wlds[512 + lane];   // de-MLP base

    float* __restrict__ yout = out;                       // [NMAX+1][n]
    float* __restrict__ vout = out + (size_t)(NMAX + 1) * n;

    // ---- split chain: val pass -> break check -> de pass only if needed ----
    float v = mlp_one(wlv, uv, y0, vb2);                  // v0
    if (lane == 0) { yout[b] = y0; vout[b] = v; }

    float y     = y0 + mlp_one(wld, ud, y0, db2);         // y1 (de always needed)
    float vprev = v;
    float yfin  = y0, vfin = v;
    int   kend  = NMAX;

    float* yp = yout + b;
    float* vp = vout + b;
    for (int k = 1; k <= NMAX; ++k) {
        yp += n; vp += n;
        const float vk = mlp_one(wlv, uv, y, vb2);        // val(y_k)
        if (lane == 0) { *yp = y; *vp = vk; }
        yfin = y; vfin = vk;
        if (k >= 2 && vk >= vprev) { kend = k; break; }   // ref: i>0 && v_new >= v_prev
        vprev = vk;
        if (k < NMAX) y += mlp_one(wld, ud, y, db2);      // de only if continuing
    }

    // ---- frozen rows: lanes store in parallel ----
    const int r = kend + 1 + lane;
    if (r <= NMAX) {
        yout[(size_t)r * n + b] = yfin;
        vout[(size_t)r * n + b] = vfin;
    }
}

extern "C" void kernel_launch(void* const* d_in, const int* in_sizes, int n_in,
                              void* d_out, int out_size, void* d_ws, size_t ws_size,
                              hipStream_t stream) {
    const float* X      = (const float*)d_in[0];
    const float* Y      = (const float*)d_in[1];
    const float* de_W1  = (const float*)d_in[2];
    const float* de_b1  = (const float*)d_in[3];
    const float* de_W2  = (const float*)d_in[4];
    const float* de_b2  = (const float*)d_in[5];
    const float* val_W1 = (const float*)d_in[6];
    const float* val_b1 = (const float*)d_in[7];
    const float* val_W2 = (const float*)d_in[8];
    const float* val_b2 = (const float*)d_in[9];
    float* out = (float*)d_out;

    const int n = in_sizes[0];               // 16384 samples
    dim3 block(256);                          // 4 waves/block, 1 wave = 1 sample
    dim3 grid((n + 3) / 4);
    hipLaunchKernelGGL(rmodel_kernel, grid, block, 0, stream,
                       X, Y, de_W1, de_b1, de_W2, de_b2,
                       val_W1, val_b1, val_W2, val_b2, out, n);
}